// Round 1
// baseline (158.700 us; speedup 1.0000x reference)
//
#include <hip/hip_runtime.h>
#include <math.h>

// OscillatorBank: B=16, T=500, H=100, HOP=64 -> out [B, T*HOP] f32.
// phase(b, t*64+j, h) = 64*S_{t-1}[b,h] + (j+1)*w[b,t,h],  S = prefix sum of w over t.
// Scan done in double (exact); jax f32 cumsum error avoided; np(f64) ref matched.

#define OB_B 16
#define OB_T 500
#define OB_H 100
#define OB_HOP 64
#define OB_BTH (OB_B * OB_T * OB_H)

constexpr double TWO_PI_D = 6.283185307179586476925286766559;
constexpr double SR_D     = 44100.0;
constexpr double NYQ_D    = 22050.0;

// Kernel A: per (b,t,h) compute w (double, rad/sample) and c = loud*amp_masked/H.
__global__ void ob_prepare(const float* __restrict__ f0,
                           const float* __restrict__ loud,
                           const float* __restrict__ amps,
                           const float* __restrict__ stretch,
                           double* __restrict__ w_d,
                           float* __restrict__ c)
{
    int idx = blockIdx.x * blockDim.x + threadIdx.x;
    if (idx >= OB_BTH) return;
    int h  = idx % OB_H;        // 0..99 -> harmonic index h+1
    int bt = idx / OB_H;        // b*T + t
    double st   = (double)stretch[bt];
    double harm = pow((double)(h + 1), 1.0 + st) * (double)f0[bt];  // Hz
    w_d[idx] = harm * (TWO_PI_D / SR_D);
    float cv = (harm > NYQ_D) ? 0.0f : (loud[bt] * amps[idx] * (1.0f / OB_H));
    c[idx] = cv;
}

// Kernel B: serial scan over t per (b,h). base[b,t,h] = (64 * S_{t-1}) mod 2pi.
__global__ void ob_scan(const double* __restrict__ w_d,
                        float* __restrict__ baseq)
{
    int tid = blockIdx.x * blockDim.x + threadIdx.x;
    if (tid >= OB_B * OB_H) return;
    int b = tid / OB_H, h = tid % OB_H;
    const double* wp = w_d   + (size_t)b * OB_T * OB_H + h;
    float*        bp = baseq + (size_t)b * OB_T * OB_H + h;
    double S = 0.0;
    #pragma unroll 4
    for (int t = 0; t < OB_T; ++t) {
        double ph = 64.0 * S;
        ph -= TWO_PI_D * trunc(ph / TWO_PI_D);   // reduce mod 2pi (exact in double)
        bp[(size_t)t * OB_H] = (float)ph;
        S += wp[(size_t)t * OB_H];
    }
}

// Kernel C: one 64-thread block per hop (b,t). Thread j = sample within hop.
__global__ void __launch_bounds__(64)
ob_synth(const double* __restrict__ w_d,
         const float* __restrict__ c,
         const float* __restrict__ baseq,
         float* __restrict__ out)
{
    int bt = blockIdx.x;        // b*T + t
    int j  = threadIdx.x;       // 0..63
    __shared__ float sw[OB_H], sc[OB_H], sb[OB_H];
    size_t row = (size_t)bt * OB_H;
    for (int i = j; i < OB_H; i += 64) {
        sw[i] = (float)w_d[row + i];
        sc[i] = c[row + i];
        sb[i] = baseq[row + i];
    }
    __syncthreads();
    float jf = (float)(j + 1);
    float s = 0.0f;
    #pragma unroll 4
    for (int h = 0; h < OB_H; ++h)
        s += sc[h] * sinf(sb[h] + jf * sw[h]);
    // out[b, t*64 + j] ; (b*T+t)*64 + j == b*32000 + t*64 + j
    out[(size_t)bt * OB_HOP + j] = s;
}

extern "C" void kernel_launch(void* const* d_in, const int* in_sizes, int n_in,
                              void* d_out, int out_size, void* d_ws, size_t ws_size,
                              hipStream_t stream)
{
    const float* f0      = (const float*)d_in[0];
    const float* loud    = (const float*)d_in[1];
    const float* amps    = (const float*)d_in[2];
    const float* stretch = (const float*)d_in[3];

    double* w_d   = (double*)d_ws;                 // 800000 * 8B = 6.4 MB
    float*  c     = (float*)(w_d + OB_BTH);        // 3.2 MB
    float*  baseq = c + OB_BTH;                    // 3.2 MB
    float*  out   = (float*)d_out;

    ob_prepare<<<(OB_BTH + 255) / 256, 256, 0, stream>>>(f0, loud, amps, stretch, w_d, c);
    ob_scan<<<(OB_B * OB_H + 255) / 256, 256, 0, stream>>>(w_d, baseq);
    ob_synth<<<OB_B * OB_T, 64, 0, stream>>>(w_d, c, baseq, out);
}

// Round 2
// 84.099 us; speedup vs baseline: 1.8871x; 1.8871x over previous
//
#include <hip/hip_runtime.h>
#include <math.h>

// OscillatorBank: B=16, T=500, H=100, HOP=64 -> out [B, T*HOP] f32.
// phase(b, t*64+j, h) = 64*S_{t-1}[b,h] + (j+1)*w[b,t,h],  S = prefix sum of w over t.
// R1: fused prepare+scan (1 wave per (b,h), shfl-scan in double, exp2 instead of pow),
//     synth uses native __sinf; c computed in synth (coalesced amps read).

#define OB_B 16
#define OB_T 500
#define OB_H 100
#define OB_HOP 64

constexpr double TWO_PI_D  = 6.283185307179586476925286766559;
constexpr double INV_2PI_D = 0.15915494309189533576888376337251;
constexpr double SR_D      = 44100.0;
constexpr float  PI_F      = 3.14159265358979f;

// Kernel 1: one wave per (b,h). Lane l handles t in [8l, 8l+8).
// Computes w = h^(1+stretch)*f0 * 2pi/SR in double (exp2 with wave-uniform log2(h)),
// wave-scans chunk sums, writes base=(64*S_{t-1} mod 2pi) and w as f32, layout [b,t,h].
__global__ void __launch_bounds__(256)
ob_scan_fused(const float* __restrict__ f0,
              const float* __restrict__ stretch,
              float* __restrict__ w_f,
              float* __restrict__ base_f)
{
    int wave = threadIdx.x >> 6;
    int lane = threadIdx.x & 63;
    int bh   = blockIdx.x * 4 + wave;      // 0..1599
    int b = bh / OB_H, h = bh % OB_H;
    double L = log2((double)(h + 1));      // wave-uniform
    const float* f0b = f0      + b * OB_T;
    const float* stb = stretch + b * OB_T;

    double w[8];
    double csum = 0.0;
    int t0 = lane * 8;
    #pragma unroll
    for (int k = 0; k < 8; ++k) {
        int t = t0 + k;
        double wv = 0.0;
        if (t < OB_T) {
            double harm = exp2((1.0 + (double)stb[t]) * L) * (double)f0b[t]; // Hz
            wv = harm * (TWO_PI_D / SR_D);
        }
        w[k] = wv;
        csum += wv;
    }
    // inclusive wave scan of chunk sums (double shuffles)
    double incl = csum;
    #pragma unroll
    for (int off = 1; off < 64; off <<= 1) {
        double up = __shfl_up(incl, (unsigned)off, 64);
        if (lane >= off) incl += up;
    }
    double S = incl - csum;                // exclusive prefix: sum of w for t < t0
    size_t rowbase = (size_t)b * OB_T * OB_H + h;
    #pragma unroll
    for (int k = 0; k < 8; ++k) {
        int t = t0 + k;
        if (t < OB_T) {
            double ph = 64.0 * S;
            // reduce mod 2pi; an off-by-one period from the fast trunc is harmless (sin periodic)
            ph -= TWO_PI_D * trunc(ph * INV_2PI_D);
            size_t idx = rowbase + (size_t)t * OB_H;
            base_f[idx] = (float)ph;
            w_f[idx]    = (float)w[k];
            S += w[k];
        }
    }
}

// Kernel 2: one 64-thread block per hop (b,t); thread j = sample in hop.
__global__ void __launch_bounds__(64)
ob_synth(const float* __restrict__ w_f,
         const float* __restrict__ base_f,
         const float* __restrict__ amps,
         const float* __restrict__ loud,
         float* __restrict__ out)
{
    int bt = blockIdx.x;                   // b*T + t
    int j  = threadIdx.x;                  // 0..63
    __shared__ float sw[OB_H], sb[OB_H], sc[OB_H];
    size_t row = (size_t)bt * OB_H;
    float ld = loud[bt];
    for (int i = j; i < OB_H; i += 64) {
        float wv = w_f[row + i];
        sw[i] = wv;
        sb[i] = base_f[row + i];
        sc[i] = (wv > PI_F) ? 0.0f : ld * amps[row + i] * (1.0f / OB_H);
    }
    __syncthreads();
    float jf = (float)(j + 1);
    float s = 0.0f;
    #pragma unroll
    for (int h = 0; h < OB_H; ++h)
        s += sc[h] * __sinf(sb[h] + jf * sw[h]);   // native v_sin_f32; args < ~98 rad
    out[(size_t)bt * OB_HOP + j] = s;              // == out[b, t*64+j]
}

extern "C" void kernel_launch(void* const* d_in, const int* in_sizes, int n_in,
                              void* d_out, int out_size, void* d_ws, size_t ws_size,
                              hipStream_t stream)
{
    const float* f0      = (const float*)d_in[0];
    const float* loud    = (const float*)d_in[1];
    const float* amps    = (const float*)d_in[2];
    const float* stretch = (const float*)d_in[3];

    float* w_f    = (float*)d_ws;                      // 3.2 MB
    float* base_f = w_f + (size_t)OB_B * OB_T * OB_H;  // 3.2 MB
    float* out    = (float*)d_out;

    ob_scan_fused<<<(OB_B * OB_H) / 4, 256, 0, stream>>>(f0, stretch, w_f, base_f);
    ob_synth<<<OB_B * OB_T, 64, 0, stream>>>(w_f, base_f, amps, loud, out);
}